// Round 4
// baseline (93.876 us; speedup 1.0000x reference)
//
#include <hip/hip_runtime.h>
#include <math.h>

#define N_NODES 8192
#define KNN 9

// Fully-unrolled, statically-indexed carry-bubble insert into sorted-ascending
// top-9 (strict <, so equal keys keep the incumbent = lower index first, which
// matches jax.lax.top_k tie-breaking when candidates arrive in ascending index
// order).
__device__ __forceinline__ void insert9(float (&td)[9], int (&ti)[9], float d, int idx) {
  float cd = d; int ci = idx;
#pragma unroll
  for (int k = 0; k < 9; ++k) {
    bool c = cd < td[k];
    float od = td[k]; int oi = ti[k];
    td[k] = c ? cd : od;  ti[k] = c ? ci : oi;
    cd = c ? od : cd;     ci = c ? oi : ci;
  }
}

// K1: x[B,C,H,W] -> xf[N,C] via LDS tile transpose (coalesced both ways);
// sq[n] = ||xf[n]||^2 ; zero deg.
__global__ __launch_bounds__(256) void k_prep(const float* __restrict__ x,
                                              float* __restrict__ xf,
                                              float* __restrict__ sq,
                                              int* __restrict__ deg) {
  __shared__ float t[64][65];
  const int b = blockIdx.x >> 4;
  const int hw0 = (blockIdx.x & 15) * 64;
  const int c0 = threadIdx.x >> 6;      // 0..3
  const int hwl = threadIdx.x & 63;
#pragma unroll
  for (int i = 0; i < 16; ++i) {
    int c = i * 4 + c0;
    t[c][hwl] = x[((size_t)(b * 64 + c)) * 1024 + hw0 + hwl];
  }
  __syncthreads();
  const int wave = threadIdx.x >> 6;    // 0..3
  const int lane = threadIdx.x & 63;    // channel
#pragma unroll
  for (int i = 0; i < 16; ++i) {
    int r = i * 4 + wave;               // hw row within tile
    float v = t[lane][r];
    int n = b * 1024 + hw0 + r;
    xf[(size_t)n * 64 + lane] = v;      // lanes along c -> 256B contiguous
    float s = v * v;
#pragma unroll
    for (int m = 1; m < 64; m <<= 1) s += __shfl_xor(s, m);
    if (lane == 0) sq[n] = s;
  }
  int tid = blockIdx.x * 256 + threadIdx.x;
  if (tid < N_NODES) deg[tid] = 0;
}

// K2: per-batch chunked KNN, no LDS. Each thread owns one query; its vector is
// PINNED in 64 VGPRs (asm def blocks load rematerialization — round-3 counters
// showed VGPR_Count=64, i.e. the compiler was re-loading qv per candidate).
// Candidate index is wave-uniform -> readfirstlane -> scalar/broadcast loads.
// Partials are written QUERY-MAJOR: pd[(q*P+p)*9 + k].
__global__ __launch_bounds__(256, 4) void k_knn(const float* __restrict__ xf,
                                                const float* __restrict__ sq,
                                                float* __restrict__ pd,
                                                int* __restrict__ pi, int P) {
  const int qbase = blockIdx.x * 256;
  const int p = blockIdx.y;
  const int q = qbase + (int)threadIdx.x;
  const int b = (8 * qbase) / 8191;
  const int bstart = (b * 8191 + 7) / 8;            // ceil(b*8191/8)
  int bend = ((b + 1) * 8191 + 7) / 8;              // start of next batch
  if (bend > N_NODES - 1) bend = N_NODES - 1;       // exclude node 8191 (batch 8)

  const int len = bend - bstart;
  const int csz = (len + P - 1) / P;
  const int cs = bstart + p * csz;
  const int ce = min(cs + csz, bend);

  float qv[64];
  const float4* qp = reinterpret_cast<const float4*>(xf + (size_t)q * 64);
#pragma unroll
  for (int i = 0; i < 16; ++i) {
    float4 v = qp[i];
    qv[4 * i + 0] = v.x; qv[4 * i + 1] = v.y; qv[4 * i + 2] = v.z; qv[4 * i + 3] = v.w;
  }
  // Pin qv in VGPRs: asm redefinition makes rematerializing the loads illegal.
#pragma unroll
  for (int i = 0; i < 64; ++i) asm volatile("" : "+v"(qv[i]));
  const float sqq = sq[q];

  float td[9]; int ti[9];
#pragma unroll
  for (int k = 0; k < 9; ++k) { td[k] = 3.0e38f; ti[k] = 0x7fffffff; }

#pragma unroll 2
  for (int j = cs; j < ce; ++j) {
    const int cj = __builtin_amdgcn_readfirstlane(j);   // wave-uniform candidate
    const float4* cp = reinterpret_cast<const float4*>(xf + (size_t)cj * 64);
    float a0 = 0.f, a1 = 0.f, a2 = 0.f, a3 = 0.f;
#pragma unroll
    for (int i = 0; i < 16; ++i) {
      float4 v = cp[i];                                 // uniform-addr broadcast
      a0 = fmaf(qv[4 * i + 0], v.x, a0);
      a1 = fmaf(qv[4 * i + 1], v.y, a1);
      a2 = fmaf(qv[4 * i + 2], v.z, a2);
      a3 = fmaf(qv[4 * i + 3], v.w, a3);
    }
    float dot = (a0 + a1) + (a2 + a3);
    float d2 = fmaf(-2.f, dot, sqq + sq[cj]);
    if (d2 < td[8]) insert9(td, ti, d2, j);
  }

  if (q != N_NODES - 1) {
    size_t base = ((size_t)q * P + p) * KNN;
#pragma unroll
    for (int k = 0; k < 9; ++k) { pd[base + k] = td[k]; pi[base + k] = ti[k]; }
  }
}

// K3: wave-cooperative P-way merge. One wave per query (4 queries/block).
// Lane p holds partial list p (sorted); 9 rounds of 5-step shfl argmin over
// (d, lane) — lower lane wins ties = lower chunk = lower candidate index,
// matching top_k order. Winning lane pops its head via static unrolled shift.
__global__ __launch_bounds__(256) void k_merge(const float* __restrict__ pd,
                                               const int* __restrict__ pi,
                                               int* __restrict__ idxf,
                                               int* __restrict__ deg, int P) {
  const int lane = threadIdx.x & 63;
  const int q = blockIdx.x * 4 + (threadIdx.x >> 6);

  if (q == N_NODES - 1) {
    // batch 8 = {8191}: self first, then -inf ties filled with indices 0..7
    if (lane < KNN) {
      int s = (lane == 0) ? (N_NODES - 1) : (lane - 1);
      idxf[q * KNN + lane] = s;
      if (s != q) atomicAdd(&deg[s], 1);
    }
    return;
  }

  float ld[9]; int li[9];
  {
    int pl = lane < P ? lane : (P - 1);
    size_t base = ((size_t)q * P + pl) * KNN;
#pragma unroll
    for (int k = 0; k < 9; ++k) { ld[k] = pd[base + k]; li[k] = pi[base + k]; }
    if (lane >= P) {
#pragma unroll
      for (int k = 0; k < 9; ++k) ld[k] = 3.2e38f;
    }
  }

#pragma unroll
  for (int r = 0; r < 9; ++r) {
    float d = ld[0]; int bi = li[0]; int bl = lane;
#pragma unroll
    for (int m = 1; m < 32; m <<= 1) {
      float od = __shfl_xor(d, m);
      int obi = __shfl_xor(bi, m);
      int obl = __shfl_xor(bl, m);
      bool take = (od < d) || (od == d && obl < bl);
      d = take ? od : d; bi = take ? obi : bi; bl = take ? obl : bl;
    }
    if (lane == r) {
      idxf[q * KNN + r] = bi;
      if (bi != q) atomicAdd(&deg[bi], 1);
    }
    if (lane == bl) {
#pragma unroll
      for (int k = 0; k < 8; ++k) { ld[k] = ld[k + 1]; li[k] = li[k + 1]; }
      ld[8] = 3.2e38f;
    }
  }
}

// K4 (fused gather + output GEMM):
// phase 1: g[t] = sum_k (-dis[s_k] * dis[t]) * xf[s_k]  -> straight into LDS
// phase 2: out = xf @ W0 + g @ W1 + bias
__global__ __launch_bounds__(256) void k_gout(const float* __restrict__ xf,
                                              const int* __restrict__ idxf,
                                              const int* __restrict__ deg,
                                              const float* __restrict__ W0,
                                              const float* __restrict__ W1,
                                              const float* __restrict__ bias,
                                              float* __restrict__ out) {
  __shared__ float w0[64 * 64];
  __shared__ float w1[64 * 64];
  __shared__ float sx[16 * 65];   // +1 pad: kills 4-way bank conflict on row reads
  __shared__ float sg[16 * 65];
  const int nb = blockIdx.x * 16;

  float4* w04 = reinterpret_cast<float4*>(w0);
  float4* w14 = reinterpret_cast<float4*>(w1);
  const float4* W04 = reinterpret_cast<const float4*>(W0);
  const float4* W14 = reinterpret_cast<const float4*>(W1);
  for (int t = threadIdx.x; t < 1024; t += 256) { w04[t] = W04[t]; w14[t] = W14[t]; }
  for (int t = threadIdx.x; t < 1024; t += 256) {
    int ln = t >> 6, c = t & 63;
    sx[ln * 65 + c] = xf[(size_t)(nb + ln) * 64 + c];
  }
  {
    int ln = threadIdx.x >> 4, c4 = threadIdx.x & 15;
    int n = nb + ln;
    int dt = deg[n];
    float dis_t = dt > 0 ? 1.f / sqrtf((float)dt) : 0.f;
    float ax = 0.f, ay = 0.f, az = 0.f, aw = 0.f;
#pragma unroll
    for (int k = 0; k < 9; ++k) {
      int s = idxf[n * KNN + k];
      if (s == n) continue;                    // self loop: w=0 -> norm 0
      int ds = deg[s];
      float dis_s = ds > 0 ? 1.f / sqrtf((float)ds) : 0.f;
      float w = -dis_s * dis_t;
      float4 v = reinterpret_cast<const float4*>(xf + (size_t)s * 64)[c4];
      ax = fmaf(w, v.x, ax); ay = fmaf(w, v.y, ay);
      az = fmaf(w, v.z, az); aw = fmaf(w, v.w, aw);
    }
    sg[ln * 65 + c4 * 4 + 0] = ax;
    sg[ln * 65 + c4 * 4 + 1] = ay;
    sg[ln * 65 + c4 * 4 + 2] = az;
    sg[ln * 65 + c4 * 4 + 3] = aw;
  }
  __syncthreads();
  int ln = threadIdx.x >> 4, o4 = threadIdx.x & 15;
  float4 acc = reinterpret_cast<const float4*>(bias)[o4];
#pragma unroll
  for (int c = 0; c < 64; ++c) {
    float xv = sx[ln * 65 + c];
    float gv = sg[ln * 65 + c];
    float4 v0 = reinterpret_cast<const float4*>(w0 + c * 64)[o4];
    float4 v1 = reinterpret_cast<const float4*>(w1 + c * 64)[o4];
    acc.x = fmaf(xv, v0.x, acc.x); acc.y = fmaf(xv, v0.y, acc.y);
    acc.z = fmaf(xv, v0.z, acc.z); acc.w = fmaf(xv, v0.w, acc.w);
    acc.x = fmaf(gv, v1.x, acc.x); acc.y = fmaf(gv, v1.y, acc.y);
    acc.z = fmaf(gv, v1.z, acc.z); acc.w = fmaf(gv, v1.w, acc.w);
  }
  reinterpret_cast<float4*>(out)[(size_t)(nb + ln) * 16 + o4] = acc;
}

extern "C" void kernel_launch(void* const* d_in, const int* in_sizes, int n_in,
                              void* d_out, int out_size, void* d_ws, size_t ws_size,
                              hipStream_t stream) {
  const float* x    = (const float*)d_in[0];
  const float* W0   = (const float*)d_in[1];
  const float* W1   = (const float*)d_in[2];
  const float* bias = (const float*)d_in[3];
  float* out = (float*)d_out;
  char* ws = (char*)d_ws;

  // workspace layout
  float* xf   = (float*)(ws);                       // 8192*64*4 = 2,097,152
  float* sq   = (float*)(ws + 2097152);             // 32,768
  int*   deg  = (int*)  (ws + 2129920);             // 32,768
  int*   idxf = (int*)  (ws + 2162688);             // 8192*9*4 = 294,912
  char*  pbase = ws + 2457600;                      // partial top-9 lists

  int P = 32;   // candidate chunks (occupancy lever for k_knn; merge needs <=32)
  while (P > 1) {
    size_t need = 2457600 + (size_t)P * N_NODES * KNN * 8;
    if (need <= ws_size) break;
    P >>= 1;
  }
  float* pd = (float*)pbase;
  int*   pi = (int*)(pbase + (size_t)P * N_NODES * KNN * 4);

  k_prep  <<<128, 256, 0, stream>>>(x, xf, sq, deg);
  k_knn   <<<dim3(32, P), 256, 0, stream>>>(xf, sq, pd, pi, P);
  k_merge <<<2048, 256, 0, stream>>>(pd, pi, idxf, deg, P);
  k_gout  <<<512, 256, 0, stream>>>(xf, idxf, deg, W0, W1, bias, out);
}

// Round 5
// 88.826 us; speedup vs baseline: 1.0569x; 1.0569x over previous
//
#include <hip/hip_runtime.h>
#include <math.h>

#define N_NODES 8192
#define KNN 9

// Fully-unrolled, statically-indexed carry-bubble insert into sorted-ascending
// top-9 (strict <, so equal keys keep the incumbent = lower index first, which
// matches jax.lax.top_k tie-breaking when candidates arrive in ascending index
// order).
__device__ __forceinline__ void insert9(float (&td)[9], int (&ti)[9], float d, int idx) {
  float cd = d; int ci = idx;
#pragma unroll
  for (int k = 0; k < 9; ++k) {
    bool c = cd < td[k];
    float od = td[k]; int oi = ti[k];
    td[k] = c ? cd : od;  ti[k] = c ? ci : oi;
    cd = c ? od : cd;     ci = c ? oi : ci;
  }
}

// K1: x[B,C,H,W] -> xf[N,C] via LDS tile transpose (coalesced both ways);
// sq[n] = ||xf[n]||^2 ; zero deg.
__global__ __launch_bounds__(256) void k_prep(const float* __restrict__ x,
                                              float* __restrict__ xf,
                                              float* __restrict__ sq,
                                              int* __restrict__ deg) {
  __shared__ float t[64][65];
  const int b = blockIdx.x >> 4;
  const int hw0 = (blockIdx.x & 15) * 64;
  const int c0 = threadIdx.x >> 6;      // 0..3
  const int hwl = threadIdx.x & 63;
#pragma unroll
  for (int i = 0; i < 16; ++i) {
    int c = i * 4 + c0;
    t[c][hwl] = x[((size_t)(b * 64 + c)) * 1024 + hw0 + hwl];
  }
  __syncthreads();
  const int wave = threadIdx.x >> 6;    // 0..3
  const int lane = threadIdx.x & 63;    // channel
#pragma unroll
  for (int i = 0; i < 16; ++i) {
    int r = i * 4 + wave;               // hw row within tile
    float v = t[lane][r];
    int n = b * 1024 + hw0 + r;
    xf[(size_t)n * 64 + lane] = v;      // lanes along c -> 256B contiguous
    float s = v * v;
#pragma unroll
    for (int m = 1; m < 64; m <<= 1) s += __shfl_xor(s, m);
    if (lane == 0) sq[n] = s;
  }
  int tid = blockIdx.x * 256 + threadIdx.x;
  if (tid < N_NODES) deg[tid] = 0;
}

// K2: register-tiled distance GEMM + in-LDS selection.
// Block = 128 queries x csz candidates (tiles of 64), K=64 channels.
// Thread (tq,tc4) accumulates an 8x4 d2 micro-tile => LDS bytes amortized
// ~4x vs the old one-thread-one-query scheme (which was LDS-pipe-bound at
// 16 ds_read_b128 per wave-candidate ~= 41us/CU).
// x is [B,C,H,W] = channel-major per batch, which IS the K-major layout the
// tiles need -> Q/C stage directly from x, coalesced, no transpose.
// Selection: d2 stash in LDS (2 phases of 32 cands); wave-pair `sub`== tile
// parity scans, keeping one private sorted top-9 per (query, tile-parity).
// Lists are contiguous ascending candidate ranges ordered by (p, sub) =>
// exact top_k tie semantics preserved in the merge.
__global__ __launch_bounds__(256, 2) void k_knn(const float* __restrict__ x,
                                                const float* __restrict__ sq,
                                                float* __restrict__ pd,
                                                int* __restrict__ pi, int P) {
  __shared__ float Qs[64][128];    // 32KB, K-major
  __shared__ float Cs[32][64];     // 8KB,  K-major (half-K, staged twice)
  __shared__ float st[128][36];    // 18KB, d2 stash (b128-aligned rows)
  __shared__ float sqq_l[128];
  __shared__ float lsq[64];

  const int t = threadIdx.x;
  const int b = blockIdx.x >> 3;           // batch 0..7
  const int qt = blockIdx.x & 7;           // query tile within batch
  const int p = blockIdx.y;                // candidate chunk

  const int bstart = b << 10;              // batch boundaries are exactly 1024*b
  const int bend = (b == 7) ? 8191 : (bstart + 1024);   // node 8191 = batch 8
  const int csz = (1024 + P - 1) / P;
  const int cs = bstart + p * csz;
  const int ce = min(cs + csz, bend);
  const int q0 = bstart + (qt << 7);

  // stage Q tile (coalesced): Qs[k][c] = x[b][k][qt*128 + c]
  {
    const float4* xs = reinterpret_cast<const float4*>(x) +
                       ((size_t)b * 65536 + (qt << 7)) / 4;
#pragma unroll
    for (int i = 0; i < 8; ++i) {
      int idx = i * 256 + t;
      int k = idx >> 5, c4 = idx & 31;
      float4 v = xs[(size_t)k * 256 + c4];
      *reinterpret_cast<float4*>(&Qs[k][c4 * 4]) = v;
    }
  }
  if (t < 128) sqq_l[t] = sq[q0 + t];

  const int tq = t >> 4;          // 0..15 -> query cols tq*8..+7
  const int tc4 = t & 15;         // 0..15 -> cand cols tc4*4..+3
  const int sub = t >> 7;         // scanning wave-pair == tile parity
  const int qid = t & 127;

  float td[9]; int ti[9];
#pragma unroll
  for (int k = 0; k < 9; ++k) { td[k] = 3.0e38f; ti[k] = 0x7fffffff; }

  int tl = 0;
  for (int ts = cs; ts < ce; ts += 64, ++tl) {
    const int tc = min(64, ce - ts);
    __syncthreads();                      // prev tile fully done; Qs ready
    if (t < tc) lsq[t] = sq[ts + t];

    float acc[8][4];
#pragma unroll
    for (int i = 0; i < 8; ++i)
#pragma unroll
      for (int j = 0; j < 4; ++j) acc[i][j] = 0.f;

#pragma unroll
    for (int kh = 0; kh < 2; ++kh) {
      // stage C half-K (coalesced; reads stay in-bounds even for tc=63 since
      // row ts..ts+63 is within the batch's hw range; junk cols masked in scan)
      {
        const float4* xs = reinterpret_cast<const float4*>(x) +
                           ((size_t)b * 65536 + (size_t)kh * 32768 + (ts - bstart)) / 4;
#pragma unroll
        for (int i = 0; i < 2; ++i) {
          int idx = i * 256 + t;
          int k = idx >> 4, c4 = idx & 15;
          float4 v = xs[(size_t)k * 256 + c4];
          *reinterpret_cast<float4*>(&Cs[k][c4 * 4]) = v;
        }
      }
      __syncthreads();
#pragma unroll 2
      for (int k = 0; k < 32; ++k) {
        float4 qa = *reinterpret_cast<const float4*>(&Qs[kh * 32 + k][tq * 8]);
        float4 qb = *reinterpret_cast<const float4*>(&Qs[kh * 32 + k][tq * 8 + 4]);
        float4 cf = *reinterpret_cast<const float4*>(&Cs[k][tc4 * 4]);
        float qv[8] = {qa.x, qa.y, qa.z, qa.w, qb.x, qb.y, qb.z, qb.w};
        float cv[4] = {cf.x, cf.y, cf.z, cf.w};
#pragma unroll
        for (int i = 0; i < 8; ++i)
#pragma unroll
          for (int j = 0; j < 4; ++j)
            acc[i][j] = fmaf(qv[i], cv[j], acc[i][j]);
      }
      if (kh == 0) __syncthreads();       // all waves done reading Cs half 0
    }

    // selection: two phases of 32 candidates through the stash
#pragma unroll
    for (int ph = 0; ph < 2; ++ph) {
      if ((tc4 >> 3) == ph) {             // writer half of tc4 range
        float l0 = lsq[tc4 * 4 + 0], l1 = lsq[tc4 * 4 + 1];
        float l2 = lsq[tc4 * 4 + 2], l3 = lsq[tc4 * 4 + 3];
        int c0 = (tc4 - ph * 8) * 4;
#pragma unroll
        for (int i = 0; i < 8; ++i) {
          float sv = sqq_l[tq * 8 + i];
          float4 dd;
          dd.x = fmaf(-2.f, acc[i][0], sv + l0);
          dd.y = fmaf(-2.f, acc[i][1], sv + l1);
          dd.z = fmaf(-2.f, acc[i][2], sv + l2);
          dd.w = fmaf(-2.f, acc[i][3], sv + l3);
          *reinterpret_cast<float4*>(&st[tq * 8 + i][c0]) = dd;
        }
      }
      __syncthreads();                    // stash ready
      if (sub == (tl & 1)) {
        int n = min(32, tc - ph * 32);
        for (int j = 0; j < n; ++j) {
          float d = st[qid][j];
          if (d < td[8]) insert9(td, ti, d, ts + ph * 32 + j);
        }
      }
      __syncthreads();                    // scan done before next write/stage
    }
  }

  // write partial lists, query-major; list id = p*2 + sub (ascending ranges)
  {
    const int q = q0 + qid;
    if (q < bend) {
      size_t base = ((size_t)q * (2 * P) + (p * 2 + sub)) * KNN;
#pragma unroll
      for (int k = 0; k < 9; ++k) { pd[base + k] = td[k]; pi[base + k] = ti[k]; }
    }
  }
}

// K3: wave-cooperative L-way merge (L = 2P <= 32). One wave per query.
// Lane l holds sorted list l; 9 rounds of shfl argmin over (d, lane) —
// lower lane wins ties = lower candidate range = lower index, matching top_k.
__global__ __launch_bounds__(256) void k_merge(const float* __restrict__ pd,
                                               const int* __restrict__ pi,
                                               int* __restrict__ idxf,
                                               int* __restrict__ deg, int L) {
  const int lane = threadIdx.x & 63;
  const int q = blockIdx.x * 4 + (threadIdx.x >> 6);

  if (q == N_NODES - 1) {
    // batch 8 = {8191}: self first, then -inf ties filled with indices 0..7
    if (lane < KNN) {
      int s = (lane == 0) ? (N_NODES - 1) : (lane - 1);
      idxf[q * KNN + lane] = s;
      if (s != q) atomicAdd(&deg[s], 1);
    }
    return;
  }

  float ld[9]; int li[9];
  {
    int pl = lane < L ? lane : (L - 1);
    size_t base = ((size_t)q * L + pl) * KNN;
#pragma unroll
    for (int k = 0; k < 9; ++k) { ld[k] = pd[base + k]; li[k] = pi[base + k]; }
    if (lane >= L) {
#pragma unroll
      for (int k = 0; k < 9; ++k) ld[k] = 3.2e38f;
    }
  }

#pragma unroll
  for (int r = 0; r < 9; ++r) {
    float d = ld[0]; int bi = li[0]; int bl = lane;
#pragma unroll
    for (int m = 1; m < 32; m <<= 1) {
      float od = __shfl_xor(d, m);
      int obi = __shfl_xor(bi, m);
      int obl = __shfl_xor(bl, m);
      bool take = (od < d) || (od == d && obl < bl);
      d = take ? od : d; bi = take ? obi : bi; bl = take ? obl : bl;
    }
    if (lane == r) {
      idxf[q * KNN + r] = bi;
      if (bi != q) atomicAdd(&deg[bi], 1);
    }
    if (lane == bl) {
#pragma unroll
      for (int k = 0; k < 8; ++k) { ld[k] = ld[k + 1]; li[k] = li[k + 1]; }
      ld[8] = 3.2e38f;
    }
  }
}

// K4 (fused gather + output GEMM):
// phase 1: g[t] = sum_k (-dis[s_k] * dis[t]) * xf[s_k]  -> straight into LDS
// phase 2: out = xf @ W0 + g @ W1 + bias
__global__ __launch_bounds__(256) void k_gout(const float* __restrict__ xf,
                                              const int* __restrict__ idxf,
                                              const int* __restrict__ deg,
                                              const float* __restrict__ W0,
                                              const float* __restrict__ W1,
                                              const float* __restrict__ bias,
                                              float* __restrict__ out) {
  __shared__ float w0[64 * 64];
  __shared__ float w1[64 * 64];
  __shared__ float sx[16 * 65];   // +1 pad: kills 4-way bank conflict on row reads
  __shared__ float sg[16 * 65];
  const int nb = blockIdx.x * 16;

  float4* w04 = reinterpret_cast<float4*>(w0);
  float4* w14 = reinterpret_cast<float4*>(w1);
  const float4* W04 = reinterpret_cast<const float4*>(W0);
  const float4* W14 = reinterpret_cast<const float4*>(W1);
  for (int t = threadIdx.x; t < 1024; t += 256) { w04[t] = W04[t]; w14[t] = W14[t]; }
  for (int t = threadIdx.x; t < 1024; t += 256) {
    int ln = t >> 6, c = t & 63;
    sx[ln * 65 + c] = xf[(size_t)(nb + ln) * 64 + c];
  }
  {
    int ln = threadIdx.x >> 4, c4 = threadIdx.x & 15;
    int n = nb + ln;
    int dt = deg[n];
    float dis_t = dt > 0 ? 1.f / sqrtf((float)dt) : 0.f;
    float ax = 0.f, ay = 0.f, az = 0.f, aw = 0.f;
#pragma unroll
    for (int k = 0; k < 9; ++k) {
      int s = idxf[n * KNN + k];
      if (s == n) continue;                    // self loop: w=0 -> norm 0
      int ds = deg[s];
      float dis_s = ds > 0 ? 1.f / sqrtf((float)ds) : 0.f;
      float w = -dis_s * dis_t;
      float4 v = reinterpret_cast<const float4*>(xf + (size_t)s * 64)[c4];
      ax = fmaf(w, v.x, ax); ay = fmaf(w, v.y, ay);
      az = fmaf(w, v.z, az); aw = fmaf(w, v.w, aw);
    }
    sg[ln * 65 + c4 * 4 + 0] = ax;
    sg[ln * 65 + c4 * 4 + 1] = ay;
    sg[ln * 65 + c4 * 4 + 2] = az;
    sg[ln * 65 + c4 * 4 + 3] = aw;
  }
  __syncthreads();
  int ln = threadIdx.x >> 4, o4 = threadIdx.x & 15;
  float4 acc = reinterpret_cast<const float4*>(bias)[o4];
#pragma unroll
  for (int c = 0; c < 64; ++c) {
    float xv = sx[ln * 65 + c];
    float gv = sg[ln * 65 + c];
    float4 v0 = reinterpret_cast<const float4*>(w0 + c * 64)[o4];
    float4 v1 = reinterpret_cast<const float4*>(w1 + c * 64)[o4];
    acc.x = fmaf(xv, v0.x, acc.x); acc.y = fmaf(xv, v0.y, acc.y);
    acc.z = fmaf(xv, v0.z, acc.z); acc.w = fmaf(xv, v0.w, acc.w);
    acc.x = fmaf(gv, v1.x, acc.x); acc.y = fmaf(gv, v1.y, acc.y);
    acc.z = fmaf(gv, v1.z, acc.z); acc.w = fmaf(gv, v1.w, acc.w);
  }
  reinterpret_cast<float4*>(out)[(size_t)(nb + ln) * 16 + o4] = acc;
}

extern "C" void kernel_launch(void* const* d_in, const int* in_sizes, int n_in,
                              void* d_out, int out_size, void* d_ws, size_t ws_size,
                              hipStream_t stream) {
  const float* x    = (const float*)d_in[0];
  const float* W0   = (const float*)d_in[1];
  const float* W1   = (const float*)d_in[2];
  const float* bias = (const float*)d_in[3];
  float* out = (float*)d_out;
  char* ws = (char*)d_ws;

  // workspace layout
  float* xf   = (float*)(ws);                       // 8192*64*4 = 2,097,152
  float* sq   = (float*)(ws + 2097152);             // 32,768
  int*   deg  = (int*)  (ws + 2129920);             // 32,768
  int*   idxf = (int*)  (ws + 2162688);             // 8192*9*4 = 294,912
  char*  pbase = ws + 2457600;                      // partial top-9 lists

  int P = 8;                                        // cand chunks; lists L=2P
  if (2457600 + (size_t)(2 * P) * N_NODES * KNN * 8 > ws_size) P = 4;
  const int L = 2 * P;
  float* pd = (float*)pbase;
  int*   pi = (int*)(pbase + (size_t)L * N_NODES * KNN * 4);

  k_prep  <<<128, 256, 0, stream>>>(x, xf, sq, deg);
  k_knn   <<<dim3(64, P), 256, 0, stream>>>(x, sq, pd, pi, P);
  k_merge <<<2048, 256, 0, stream>>>(pd, pi, idxf, deg, L);
  k_gout  <<<512, 256, 0, stream>>>(xf, idxf, deg, W0, W1, bias, out);
}

// Round 7
// 85.768 us; speedup vs baseline: 1.0945x; 1.0357x over previous
//
#include <hip/hip_runtime.h>
#include <math.h>

#define N_NODES 8192
#define KNN 9

// Fully-unrolled, statically-indexed carry-bubble insert into sorted-ascending
// top-9 (strict <, so equal keys keep the incumbent = lower index first, which
// matches jax.lax.top_k tie-breaking when candidates arrive in ascending index
// order).
__device__ __forceinline__ void insert9(float (&td)[9], int (&ti)[9], float d, int idx) {
  float cd = d; int ci = idx;
#pragma unroll
  for (int k = 0; k < 9; ++k) {
    bool c = cd < td[k];
    float od = td[k]; int oi = ti[k];
    td[k] = c ? cd : od;  ti[k] = c ? ci : oi;
    cd = c ? od : cd;     ci = c ? oi : ci;
  }
}

// K1: x[B,C,H,W] -> xf[N,C] via LDS tile transpose (coalesced both ways);
// sq[n] = ||xf[n]||^2 ; zero deg.
__global__ __launch_bounds__(256) void k_prep(const float* __restrict__ x,
                                              float* __restrict__ xf,
                                              float* __restrict__ sq,
                                              int* __restrict__ deg) {
  __shared__ float t[64][65];
  const int b = blockIdx.x >> 4;
  const int hw0 = (blockIdx.x & 15) * 64;
  const int c0 = threadIdx.x >> 6;      // 0..3
  const int hwl = threadIdx.x & 63;
#pragma unroll
  for (int i = 0; i < 16; ++i) {
    int c = i * 4 + c0;
    t[c][hwl] = x[((size_t)(b * 64 + c)) * 1024 + hw0 + hwl];
  }
  __syncthreads();
  const int wave = threadIdx.x >> 6;    // 0..3
  const int lane = threadIdx.x & 63;    // channel
#pragma unroll
  for (int i = 0; i < 16; ++i) {
    int r = i * 4 + wave;               // hw row within tile
    float v = t[lane][r];
    int n = b * 1024 + hw0 + r;
    xf[(size_t)n * 64 + lane] = v;      // lanes along c -> 256B contiguous
    float s = v * v;
#pragma unroll
    for (int m = 1; m < 64; m <<= 1) s += __shfl_xor(s, m);
    if (lane == 0) sq[n] = s;
  }
  int tid = blockIdx.x * 256 + threadIdx.x;
  if (tid < N_NODES) deg[tid] = 0;
}

// K2: register-tiled distance GEMM + in-LDS selection.
// Block = 128 queries x csz candidates (tiles of 64), K=64 channels.
// Thread (tq,tc4) accumulates an 8x4 d2 micro-tile.
// Selection: TWO PHASES of 32 candidates through a stride-33 stash (32 live
// columns per phase -> stride 33 is legal AND scan-conflict-free: bank =
// (qid + j) % 32, 2-way across a wave = free). ALL 256 threads scan each
// phase: thread t handles query (t&127), candidates [(t>>7)*16, +16) of the
// phase. Lists per query = 2 per chunk, ascending candidate indices ->
// (d,idx)-lex sorted; merge uses (d,idx) tie-break (partition-agnostic).
__global__ __launch_bounds__(256, 2) void k_knn(const float* __restrict__ x,
                                                const float* __restrict__ sq,
                                                float* __restrict__ pd,
                                                int* __restrict__ pi, int P) {
  __shared__ float Qs[64][128];     // 32KB, K-major
  __shared__ float Cs[32][64];      // 8KB,  K-major half-K (staged twice/tile)
  __shared__ float st[128 * 33];    // 16.9KB d2 stash (32 cols live per phase)
  __shared__ float sqq_l[128];
  __shared__ float lsq[64];

  const int t = threadIdx.x;
  const int b = blockIdx.x >> 3;           // batch 0..7
  const int qt = blockIdx.x & 7;           // query tile within batch
  const int p = blockIdx.y;                // candidate chunk

  const int bstart = b << 10;
  const int bend = (b == 7) ? 8191 : (bstart + 1024);   // node 8191 = batch 8
  const int csz = 1024 / P;
  const int cs = bstart + p * csz;
  const int ce = min(cs + csz, bend);
  const int q0 = bstart + (qt << 7);

  const float4* xb = reinterpret_cast<const float4*>(x) + (size_t)b * 16384;

  // stage Q tile (coalesced): Qs[k][c] = x[b][k][qt*128 + c]
#pragma unroll
  for (int i = 0; i < 8; ++i) {
    int idx = i * 256 + t;                 // 0..2047
    int k = idx >> 5, c4 = idx & 31;
    float4 v = xb[(size_t)k * 256 + (qt << 5) + c4];
    *reinterpret_cast<float4*>(&Qs[k][c4 * 4]) = v;
  }
  if (t < 128) sqq_l[t] = sq[q0 + t];

  const int tq = t >> 4;          // 0..15 -> query rows tq*8..+7
  const int tc4 = t & 15;         // 0..15 -> cand cols tc4*4..+3
  const int half = t >> 7;        // scan sub-range owner
  const int qid = t & 127;        // scan query

  float td[9]; int ti[9];
#pragma unroll
  for (int k = 0; k < 9; ++k) { td[k] = 3.0e38f; ti[k] = 0x7fffffff; }

  for (int ts = cs; ts < ce; ts += 64) {
    const int tc = min(64, ce - ts);
    const int hw4 = (ts - bstart) >> 2;
    __syncthreads();                      // A: prev tile's phase-1 scan done
    if (t < 64) lsq[t] = sq[ts + t];

    float acc[8][4];
#pragma unroll
    for (int i = 0; i < 8; ++i)
#pragma unroll
      for (int j = 0; j < 4; ++j) acc[i][j] = 0.f;

#pragma unroll
    for (int kh = 0; kh < 2; ++kh) {
      // stage C half-K (coalesced)
#pragma unroll
      for (int i = 0; i < 2; ++i) {
        int idx = i * 256 + t;            // 0..511
        int k = idx >> 4, c4 = idx & 15;
        float4 v = xb[(size_t)(kh * 32 + k) * 256 + hw4 + c4];
        *reinterpret_cast<float4*>(&Cs[k][c4 * 4]) = v;
      }
      __syncthreads();                    // B: Cs ready (kh0 also covers lsq)
#pragma unroll 4
      for (int k = 0; k < 32; ++k) {
        float4 qa = *reinterpret_cast<const float4*>(&Qs[kh * 32 + k][tq * 8]);
        float4 qb = *reinterpret_cast<const float4*>(&Qs[kh * 32 + k][tq * 8 + 4]);
        float4 cf = *reinterpret_cast<const float4*>(&Cs[k][tc4 * 4]);
        float qv[8] = {qa.x, qa.y, qa.z, qa.w, qb.x, qb.y, qb.z, qb.w};
        float cv[4] = {cf.x, cf.y, cf.z, cf.w};
#pragma unroll
        for (int i = 0; i < 8; ++i)
#pragma unroll
          for (int j = 0; j < 4; ++j)
            acc[i][j] = fmaf(qv[i], cv[j], acc[i][j]);
      }
      if (kh == 0) __syncthreads();       // C: compute done before Cs overwrite
    }

    // selection: two phases of 32 candidates through the stash
#pragma unroll
    for (int ph = 0; ph < 2; ++ph) {
      if ((tc4 >> 3) == ph) {             // writers: cols [ph*32, ph*32+32)
        int c0 = (tc4 & 7) * 4;           // stash col of acc[.][0]
#pragma unroll
        for (int i = 0; i < 8; ++i) {
          float sv = sqq_l[tq * 8 + i];
#pragma unroll
          for (int j = 0; j < 4; ++j) {
            float d2 = fmaf(-2.f, acc[i][j], sv + lsq[tc4 * 4 + j]);
            st[(tq * 8 + i) * 33 + c0 + j] = d2;
          }
        }
      }
      __syncthreads();                    // D: stash ready
      {
        int j0 = half * 16;
        int n = min(16, tc - ph * 32 - j0);
        for (int j = 0; j < n; ++j) {
          float d = st[qid * 33 + j0 + j];
          if (d < td[8]) insert9(td, ti, d, ts + ph * 32 + j0 + j);
        }
      }
      __syncthreads();                    // E: scan done before col reuse
    }
  }

  // write partial lists, query-major; list id = p*2 + half
  {
    const int q = q0 + qid;
    if (q < bend) {
      size_t base = ((size_t)q * (2 * P) + (p * 2 + half)) * KNN;
#pragma unroll
      for (int k = 0; k < 9; ++k) { pd[base + k] = td[k]; pi[base + k] = ti[k]; }
    }
  }
}

// K3: wave-cooperative L-way merge (L <= 32). One wave per query.
// Lane l holds sorted list l; 9 rounds of shfl argmin over (d, idx) lex order
// — exactly top_k's tie semantics (lower index wins), partition-agnostic.
__global__ __launch_bounds__(256) void k_merge(const float* __restrict__ pd,
                                               const int* __restrict__ pi,
                                               int* __restrict__ idxf,
                                               int* __restrict__ deg, int L) {
  const int lane = threadIdx.x & 63;
  const int q = blockIdx.x * 4 + (threadIdx.x >> 6);

  if (q == N_NODES - 1) {
    // batch 8 = {8191}: self first, then -inf ties filled with indices 0..7
    if (lane < KNN) {
      int s = (lane == 0) ? (N_NODES - 1) : (lane - 1);
      idxf[q * KNN + lane] = s;
      if (s != q) atomicAdd(&deg[s], 1);
    }
    return;
  }

  float ld[9]; int li[9];
  {
    int pl = lane < L ? lane : (L - 1);
    size_t base = ((size_t)q * L + pl) * KNN;
#pragma unroll
    for (int k = 0; k < 9; ++k) { ld[k] = pd[base + k]; li[k] = pi[base + k]; }
    if (lane >= L) {
#pragma unroll
      for (int k = 0; k < 9; ++k) { ld[k] = 3.2e38f; li[k] = 0x7fffffff; }
    }
  }

#pragma unroll
  for (int r = 0; r < 9; ++r) {
    float d = ld[0]; int bi = li[0]; int bl = lane;
#pragma unroll
    for (int m = 1; m < 32; m <<= 1) {
      float od = __shfl_xor(d, m);
      int obi = __shfl_xor(bi, m);
      int obl = __shfl_xor(bl, m);
      bool take = (od < d) || (od == d && obi < bi);
      d = take ? od : d; bi = take ? obi : bi; bl = take ? obl : bl;
    }
    if (lane == r) {
      idxf[q * KNN + r] = bi;
      if (bi != q) atomicAdd(&deg[bi], 1);
    }
    if (lane == bl) {
#pragma unroll
      for (int k = 0; k < 8; ++k) { ld[k] = ld[k + 1]; li[k] = li[k + 1]; }
      ld[8] = 3.2e38f;
    }
  }
}

// K4 (fused gather + output GEMM):
// phase 1: g[t] = sum_k (-dis[s_k] * dis[t]) * xf[s_k]  -> straight into LDS
// phase 2: out = xf @ W0 + g @ W1 + bias
__global__ __launch_bounds__(256) void k_gout(const float* __restrict__ xf,
                                              const int* __restrict__ idxf,
                                              const int* __restrict__ deg,
                                              const float* __restrict__ W0,
                                              const float* __restrict__ W1,
                                              const float* __restrict__ bias,
                                              float* __restrict__ out) {
  __shared__ float w0[64 * 64];
  __shared__ float w1[64 * 64];
  __shared__ float sx[16 * 65];   // +1 pad: kills 4-way bank conflict on row reads
  __shared__ float sg[16 * 65];
  const int nb = blockIdx.x * 16;

  float4* w04 = reinterpret_cast<float4*>(w0);
  float4* w14 = reinterpret_cast<float4*>(w1);
  const float4* W04 = reinterpret_cast<const float4*>(W0);
  const float4* W14 = reinterpret_cast<const float4*>(W1);
  for (int t = threadIdx.x; t < 1024; t += 256) { w04[t] = W04[t]; w14[t] = W14[t]; }
  for (int t = threadIdx.x; t < 1024; t += 256) {
    int ln = t >> 6, c = t & 63;
    sx[ln * 65 + c] = xf[(size_t)(nb + ln) * 64 + c];
  }
  {
    int ln = threadIdx.x >> 4, c4 = threadIdx.x & 15;
    int n = nb + ln;
    int dt = deg[n];
    float dis_t = dt > 0 ? 1.f / sqrtf((float)dt) : 0.f;
    float ax = 0.f, ay = 0.f, az = 0.f, aw = 0.f;
#pragma unroll
    for (int k = 0; k < 9; ++k) {
      int s = idxf[n * KNN + k];
      if (s == n) continue;                    // self loop: w=0 -> norm 0
      int ds = deg[s];
      float dis_s = ds > 0 ? 1.f / sqrtf((float)ds) : 0.f;
      float w = -dis_s * dis_t;
      float4 v = reinterpret_cast<const float4*>(xf + (size_t)s * 64)[c4];
      ax = fmaf(w, v.x, ax); ay = fmaf(w, v.y, ay);
      az = fmaf(w, v.z, az); aw = fmaf(w, v.w, aw);
    }
    sg[ln * 65 + c4 * 4 + 0] = ax;
    sg[ln * 65 + c4 * 4 + 1] = ay;
    sg[ln * 65 + c4 * 4 + 2] = az;
    sg[ln * 65 + c4 * 4 + 3] = aw;
  }
  __syncthreads();
  int ln = threadIdx.x >> 4, o4 = threadIdx.x & 15;
  float4 acc = reinterpret_cast<const float4*>(bias)[o4];
#pragma unroll
  for (int c = 0; c < 64; ++c) {
    float xv = sx[ln * 65 + c];
    float gv = sg[ln * 65 + c];
    float4 v0 = reinterpret_cast<const float4*>(w0 + c * 64)[o4];
    float4 v1 = reinterpret_cast<const float4*>(w1 + c * 64)[o4];
    acc.x = fmaf(xv, v0.x, acc.x); acc.y = fmaf(xv, v0.y, acc.y);
    acc.z = fmaf(xv, v0.z, acc.z); acc.w = fmaf(xv, v0.w, acc.w);
    acc.x = fmaf(gv, v1.x, acc.x); acc.y = fmaf(gv, v1.y, acc.y);
    acc.z = fmaf(gv, v1.z, acc.z); acc.w = fmaf(gv, v1.w, acc.w);
  }
  reinterpret_cast<float4*>(out)[(size_t)(nb + ln) * 16 + o4] = acc;
}

extern "C" void kernel_launch(void* const* d_in, const int* in_sizes, int n_in,
                              void* d_out, int out_size, void* d_ws, size_t ws_size,
                              hipStream_t stream) {
  const float* x    = (const float*)d_in[0];
  const float* W0   = (const float*)d_in[1];
  const float* W1   = (const float*)d_in[2];
  const float* bias = (const float*)d_in[3];
  float* out = (float*)d_out;
  char* ws = (char*)d_ws;

  // workspace layout
  float* xf   = (float*)(ws);                       // 8192*64*4 = 2,097,152
  float* sq   = (float*)(ws + 2097152);             // 32,768
  int*   deg  = (int*)  (ws + 2129920);             // 32,768
  int*   idxf = (int*)  (ws + 2162688);             // 8192*9*4 = 294,912
  char*  pbase = ws + 2457600;                      // partial top-9 lists

  int P = 8;                                        // cand chunks; lists L=2P
  if (2457600 + (size_t)(2 * P) * N_NODES * KNN * 8 > ws_size) P = 4;
  const int L = 2 * P;
  float* pd = (float*)pbase;
  int*   pi = (int*)(pbase + (size_t)L * N_NODES * KNN * 4);

  k_prep  <<<128, 256, 0, stream>>>(x, xf, sq, deg);
  k_knn   <<<dim3(64, P), 256, 0, stream>>>(x, sq, pd, pi, P);
  k_merge <<<2048, 256, 0, stream>>>(pd, pi, idxf, deg, L);
  k_gout  <<<512, 256, 0, stream>>>(xf, idxf, deg, W0, W1, bias, out);
}